// Round 3
// baseline (884.776 us; speedup 1.0000x reference)
//
#include <hip/hip_runtime.h>

// GCNConv: out = segment_sum(ev * x[col], row) @ W,  N=100000 E=1600000 D=64 fp32.
//
// Round 3 structure:
//   out = A @ (X @ W)   (reassociated: H = X@W in bf16, agg writes out directly)
//   1) gemm_h : H[n,:] = x[n,:] @ W   -> bf16   (halves gather bytes)
//   2) bhist  : histogram of 128-row buckets (782 buckets)
//   3) bscan  : exclusive scan -> bucket bases + cursors
//   4) bscatter: chunk-local LDS histogram + ONE cursor reservation per
//      bucket per chunk -> contiguous ~10-edge runs (kills R2's 8x write amp:
//      100 MB -> ~30 MB). Record = {key=(row&127)<<17|col : int, val bf16}.
//   5) agg    : block per bucket, 32 KB LDS fp32 accumulator, ds_add_f32
//      (lane=feature, conflict-free), gather bf16 H, coalesced out writeback.

#define N_NODES 100000
#define N_EDGES 1600000
#define DF 64
#define BROWS 128
#define NBUCK 782              // ceil(100000/128)
#define CHUNK 8192             // edges per scatter/hist block
#define EPT   32               // CHUNK/256
#define NCHUNK 196             // ceil(1600000/8192)

// ws layout (bytes); total ~22.41 MB (R1 proved ws >= 25.6 MB)
#define OFF_H     0u           // 100000*64 ushort (bf16 H) = 12.8e6
#define OFF_KEYS  12800000u    // 1.6M int   = 6.4e6
#define OFF_VALS  19200000u    // 1.6M ushort= 3.2e6
#define OFF_BASES 22400000u    // 783 int
#define OFF_CURS  22403200u    // 782 int
#define OFF_CNTS  22406400u    // 782 int

__device__ __forceinline__ ushort f2bf(float f) {
    uint b = __float_as_uint(f);
    return (ushort)((b + 0x7FFFu + ((b >> 16) & 1u)) >> 16);   // RNE
}
__device__ __forceinline__ float bf2f(ushort u) {
    return __uint_as_float(((uint)u) << 16);
}

// ---- 1) H = X @ W, bf16 out. 4 rows/block, W in LDS. 25000*4 == N exactly.
__global__ __launch_bounds__(256) void gemm_h(
    const float* __restrict__ x, const float* __restrict__ w, ushort* __restrict__ H)
{
    __shared__ float ws_[DF * DF];
    __shared__ float xs[4 * DF];
    for (int i = threadIdx.x; i < DF * DF; i += 256) ws_[i] = w[i];
    int r = threadIdx.x >> 6, j = threadIdx.x & 63;
    int row = blockIdx.x * 4 + r;
    xs[r * DF + j] = x[row * DF + j];
    __syncthreads();
    float o = 0.0f;
    #pragma unroll
    for (int k = 0; k < DF; ++k) o += xs[r * DF + k] * ws_[k * DF + j];
    H[row * DF + j] = f2bf(o);
}

// ---- 2) global bucket histogram (LDS-staged)
__global__ __launch_bounds__(256) void bhist(
    const int* __restrict__ erow, int* __restrict__ cnts)
{
    __shared__ int h[NBUCK];
    for (int i = threadIdx.x; i < NBUCK; i += 256) h[i] = 0;
    __syncthreads();
    int base = blockIdx.x * CHUNK;
    int n = min(CHUNK, N_EDGES - base);
    for (int k = threadIdx.x; k < n; k += 256)
        atomicAdd(&h[erow[base + k] >> 7], 1);
    __syncthreads();
    for (int i = threadIdx.x; i < NBUCK; i += 256)
        if (h[i]) atomicAdd(&cnts[i], h[i]);
}

// ---- 3) exclusive scan of 782 counts (single 1024-thread block)
__global__ __launch_bounds__(1024) void bscan(
    const int* __restrict__ cnts, int* __restrict__ bases, int* __restrict__ curs)
{
    __shared__ int tmp[1024];
    int i = threadIdx.x;
    int v = (i < NBUCK) ? cnts[i] : 0;
    tmp[i] = v;
    __syncthreads();
    int val = v;
    for (int off = 1; off < 1024; off <<= 1) {
        int t = (i >= off) ? tmp[i - off] : 0;
        __syncthreads();
        val += t;
        tmp[i] = val;
        __syncthreads();
    }
    if (i < NBUCK) { bases[i] = val - v; curs[i] = val - v; }
    if (i == 0) bases[NBUCK] = N_EDGES;
}

// ---- 4) bucket scatter: per-chunk LDS hist -> one global reservation per
//         bucket -> contiguous runs written by one workgroup (one XCD)
__global__ __launch_bounds__(256) void bscatter(
    const int* __restrict__ erow, const int* __restrict__ ecol,
    const float* __restrict__ ev, int* __restrict__ curs,
    int* __restrict__ keys, ushort* __restrict__ vals)
{
    __shared__ int hcnt[NBUCK];
    __shared__ int roff[NBUCK];
    for (int i = threadIdx.x; i < NBUCK; i += 256) hcnt[i] = 0;
    __syncthreads();

    int base = blockIdx.x * CHUNK;
    int n = min(CHUNK, N_EDGES - base);

    int rows[EPT];
    int cnt = 0;
    for (int k = threadIdx.x, t = 0; k < n; k += 256, ++t) {
        int r = erow[base + k];
        rows[t] = r;
        atomicAdd(&hcnt[r >> 7], 1);
        cnt = t + 1;
    }
    __syncthreads();

    for (int i = threadIdx.x; i < NBUCK; i += 256) {
        int c = hcnt[i];
        if (c) roff[i] = atomicAdd(&curs[i], c);   // bulk reservation
    }
    __syncthreads();

    for (int k = threadIdx.x, t = 0; t < cnt; k += 256, ++t) {
        int r = rows[t];
        int b = r >> 7;
        int slot = atomicAdd(&roff[b], 1);
        int col = ecol[base + k];
        keys[slot] = ((r & 127) << 17) | col;
        vals[slot] = f2bf(ev[base + k]);
    }
}

// ---- 5) aggregation: block per bucket, LDS fp32 acc, direct out write
__global__ __launch_bounds__(256) void agg(
    const ushort* __restrict__ H, const int* __restrict__ bases,
    const int* __restrict__ keys, const ushort* __restrict__ vals,
    float* __restrict__ out)
{
    __shared__ float acc[BROWS * DF];   // 32 KB
    int tid = threadIdx.x;
    for (int i = tid * 4; i < BROWS * DF; i += 1024)
        *(float4*)&acc[i] = make_float4(0.f, 0.f, 0.f, 0.f);

    int b = blockIdx.x;
    int start = bases[b], end = bases[b + 1];
    int wv = tid >> 6, lane = tid & 63;
    __syncthreads();

    int e = start + wv;
    for (; e + 12 < end; e += 16) {          // 4 edges in flight per wave
        int k0 = keys[e], k1 = keys[e + 4], k2 = keys[e + 8], k3 = keys[e + 12];
        ushort v0 = vals[e], v1 = vals[e + 4], v2 = vals[e + 8], v3 = vals[e + 12];
        float h0 = bf2f(H[(k0 & 0x1FFFF) * DF + lane]);
        float h1 = bf2f(H[(k1 & 0x1FFFF) * DF + lane]);
        float h2 = bf2f(H[(k2 & 0x1FFFF) * DF + lane]);
        float h3 = bf2f(H[(k3 & 0x1FFFF) * DF + lane]);
        atomicAdd(&acc[(k0 >> 17) * DF + lane], bf2f(v0) * h0);
        atomicAdd(&acc[(k1 >> 17) * DF + lane], bf2f(v1) * h1);
        atomicAdd(&acc[(k2 >> 17) * DF + lane], bf2f(v2) * h2);
        atomicAdd(&acc[(k3 >> 17) * DF + lane], bf2f(v3) * h3);
    }
    for (; e < end; e += 4) {
        int k0 = keys[e];
        float h0 = bf2f(H[(k0 & 0x1FFFF) * DF + lane]);
        atomicAdd(&acc[(k0 >> 17) * DF + lane], bf2f(vals[e]) * h0);
    }
    __syncthreads();

    int base_row = b * BROWS;
    int nrows = min(BROWS, N_NODES - base_row);
    for (int i = tid; i < nrows * 16; i += 256) {
        int r = i >> 4, j4 = (i & 15) * 4;
        *(float4*)&out[(base_row + r) * DF + j4] = *(float4*)&acc[r * DF + j4];
    }
}

extern "C" void kernel_launch(void* const* d_in, const int* in_sizes, int n_in,
                              void* d_out, int out_size, void* d_ws, size_t ws_size,
                              hipStream_t stream)
{
    const float* x    = (const float*)d_in[0];
    const float* w    = (const float*)d_in[1];
    const float* ev   = (const float*)d_in[2];
    const int*   erow = (const int*)d_in[3];
    const int*   ecol = (const int*)d_in[4];
    float* out = (float*)d_out;

    char* ws = (char*)d_ws;
    ushort* H     = (ushort*)(ws + OFF_H);
    int*    keys  = (int*)   (ws + OFF_KEYS);
    ushort* vals  = (ushort*)(ws + OFF_VALS);
    int*    bases = (int*)   (ws + OFF_BASES);
    int*    curs  = (int*)   (ws + OFF_CURS);
    int*    cnts  = (int*)   (ws + OFF_CNTS);

    hipMemsetAsync(cnts, 0, NBUCK * sizeof(int), stream);
    gemm_h  <<<N_NODES / 4, 256, 0, stream>>>(x, w, H);
    bhist   <<<NCHUNK, 256, 0, stream>>>(erow, cnts);
    bscan   <<<1, 1024, 0, stream>>>(cnts, bases, curs);
    bscatter<<<NCHUNK, 256, 0, stream>>>(erow, ecol, ev, curs, keys, vals);
    agg     <<<NBUCK, 256, 0, stream>>>(H, bases, keys, vals, out);
}

// Round 4
// 299.708 us; speedup vs baseline: 2.9521x; 2.9521x over previous
//
#include <hip/hip_runtime.h>

// GCNConv: out = segment_sum(ev * x[col], row) @ W,  N=100000 E=1600000 D=64 fp32.
//
// Round 4: R2's wave-per-node register aggregation (proven ~110us) fused with
// R3's H=X@W bf16 reassociation (proven numerics), plus a low-write-amp CSR
// build: chunk bucket-scatter (runs) -> per-bucket IN-PLACE counting sort.
// R3 post-mortem: 782-block LDS-atomic aggregation collapsed TLP (20% occ,
// 4.5% VALU, 681us). Aggregation must stay wave-per-node, register-acc.

#define N_NODES 100000
#define N_EDGES 1600000
#define DF 64
#define BROWS 128
#define NBUCK 782              // ceil(100000/128)
#define CHUNK 8192
#define NCHUNK 196             // ceil(1600000/8192)
#define RPT 12                 // max records/thread in bsort (bucket <= 3072)

// ws layout (bytes), total ~22.81 MB
#define OFF_H     0u           // 100000*64 ushort bf16 H   = 12.8e6
#define OFF_KEYS  12800000u    // 1.6M int  {rloc<<17|col}  = 6.4e6
#define OFF_VALS  19200000u    // 1.6M ushort bf16 val      = 3.2e6
#define OFF_ENDS  22400000u    // 100000 int CSR row ends
#define OFF_BASES 22800000u    // 783 int bucket bases
#define OFF_CURS  22803200u    // 782 int bucket cursors
#define OFF_CNTS  22806400u    // 782 int bucket counts

__device__ __forceinline__ ushort f2bf(float f) {
    uint b = __float_as_uint(f);
    return (ushort)((b + 0x7FFFu + ((b >> 16) & 1u)) >> 16);   // RNE
}
__device__ __forceinline__ float bf2f(ushort u) {
    return __uint_as_float(((uint)u) << 16);
}

// ---- 1) H = X @ W -> bf16. 4 rows/block; 25000*4 == N exactly.
__global__ __launch_bounds__(256) void gemm_h(
    const float* __restrict__ x, const float* __restrict__ w, ushort* __restrict__ H)
{
    __shared__ float ws_[DF * DF];
    __shared__ float xs[4 * DF];
    for (int i = threadIdx.x; i < DF * DF; i += 256) ws_[i] = w[i];
    int r = threadIdx.x >> 6, j = threadIdx.x & 63;
    int row = blockIdx.x * 4 + r;
    xs[r * DF + j] = x[row * DF + j];
    __syncthreads();
    float o = 0.0f;
    #pragma unroll
    for (int k = 0; k < DF; ++k) o += xs[r * DF + k] * ws_[k * DF + j];
    H[row * DF + j] = f2bf(o);
}

// ---- 2) bucket histogram (LDS-staged)
__global__ __launch_bounds__(256) void bhist(
    const int* __restrict__ erow, int* __restrict__ cnts)
{
    __shared__ int h[NBUCK];
    for (int i = threadIdx.x; i < NBUCK; i += 256) h[i] = 0;
    __syncthreads();
    int base = blockIdx.x * CHUNK;
    int n = min(CHUNK, N_EDGES - base);
    for (int k = threadIdx.x; k < n; k += 256)
        atomicAdd(&h[erow[base + k] >> 7], 1);
    __syncthreads();
    for (int i = threadIdx.x; i < NBUCK; i += 256)
        if (h[i]) atomicAdd(&cnts[i], h[i]);
}

// ---- 3) exclusive scan of 782 counts -> bases, curs
__global__ __launch_bounds__(1024) void bscan(
    const int* __restrict__ cnts, int* __restrict__ bases, int* __restrict__ curs)
{
    __shared__ int tmp[1024];
    int i = threadIdx.x;
    int v = (i < NBUCK) ? cnts[i] : 0;
    tmp[i] = v;
    __syncthreads();
    int val = v;
    for (int off = 1; off < 1024; off <<= 1) {
        int t = (i >= off) ? tmp[i - off] : 0;
        __syncthreads();
        val += t;
        tmp[i] = val;
        __syncthreads();
    }
    if (i < NBUCK) { bases[i] = val - v; curs[i] = val - v; }
    if (i == 0) bases[NBUCK] = N_EDGES;
}

// ---- 4) chunk scatter into buckets: one bulk reservation per bucket/chunk
//         -> ~10-record contiguous runs (low write-amp)
__global__ __launch_bounds__(256) void bscatter(
    const int* __restrict__ erow, const int* __restrict__ ecol,
    const float* __restrict__ ev, int* __restrict__ curs,
    int* __restrict__ keys, ushort* __restrict__ vals)
{
    __shared__ int hcnt[NBUCK];
    __shared__ int roff[NBUCK];
    for (int i = threadIdx.x; i < NBUCK; i += 256) hcnt[i] = 0;
    __syncthreads();
    int base = blockIdx.x * CHUNK;
    int n = min(CHUNK, N_EDGES - base);
    for (int k = threadIdx.x; k < n; k += 256)
        atomicAdd(&hcnt[erow[base + k] >> 7], 1);
    __syncthreads();
    for (int i = threadIdx.x; i < NBUCK; i += 256) {
        int c = hcnt[i];
        roff[i] = c ? atomicAdd(&curs[i], c) : 0;
    }
    __syncthreads();
    for (int k = threadIdx.x; k < n; k += 256) {
        int r = erow[base + k];                  // L1/L2-hot re-read
        int slot = atomicAdd(&roff[r >> 7], 1);
        keys[slot] = ((r & 127) << 17) | ecol[base + k];
        vals[slot] = f2bf(ev[base + k]);
    }
}

// ---- 5) per-bucket IN-PLACE counting sort + emit per-node CSR ends.
//         Records staged in registers; barrier; scatter within the bucket's
//         own window (single block / single XCD -> L2 merges writes).
__global__ __launch_bounds__(256) void bsort(
    const int* __restrict__ bases, int* __restrict__ keys,
    ushort* __restrict__ vals, int* __restrict__ ends)
{
    __shared__ int hist[BROWS];
    __shared__ int scan_s[BROWS];
    __shared__ int cur[BROWS];
    int b = blockIdx.x, tid = threadIdx.x;
    int s = bases[b], e = bases[b + 1];
    if (tid < BROWS) hist[tid] = 0;
    __syncthreads();

    int k[RPT]; ushort v[RPT]; int cnt = 0;
    for (int i = s + tid; i < e && cnt < RPT; i += 256, ++cnt) {
        k[cnt] = keys[i];
        v[cnt] = vals[i];
        atomicAdd(&hist[k[cnt] >> 17], 1);
    }
    __syncthreads();

    if (tid < BROWS) scan_s[tid] = hist[tid];
    __syncthreads();
    for (int off = 1; off < BROWS; off <<= 1) {   // inclusive Hillis-Steele
        int t = (tid < BROWS && tid >= off) ? scan_s[tid - off] : 0;
        __syncthreads();
        if (tid < BROWS) scan_s[tid] += t;
        __syncthreads();
    }
    if (tid < BROWS) {
        cur[tid] = s + scan_s[tid] - hist[tid];   // global start of row's segment
        int node = b * BROWS + tid;
        if (node < N_NODES) ends[node] = s + scan_s[tid];
    }
    __syncthreads();

    for (int t = 0; t < cnt; ++t) {               // all reads done before here
        int slot = atomicAdd(&cur[k[t] >> 17], 1);
        keys[slot] = k[t];
        vals[slot] = v[t];
    }
}

// ---- 6) wave-per-node aggregation: register acc, 8 gathers in flight,
//         direct coalesced out write. 25000*4 == N exactly.
__global__ __launch_bounds__(256) void agg(
    const ushort* __restrict__ H, const int* __restrict__ ends,
    const int* __restrict__ keys, const ushort* __restrict__ vals,
    float* __restrict__ out)
{
    int wv = threadIdx.x >> 6, lane = threadIdx.x & 63;
    int node = blockIdx.x * 4 + wv;
    int end = ends[node];
    int start = (node == 0) ? 0 : ends[node - 1];

    float acc = 0.0f;
    int i = start;
    for (; i + 8 <= end; i += 8) {
        int kk[8]; float vv[8]; float hv[8];
        #pragma unroll
        for (int j = 0; j < 8; ++j) kk[j] = keys[i + j];
        #pragma unroll
        for (int j = 0; j < 8; ++j) vv[j] = bf2f(vals[i + j]);
        #pragma unroll
        for (int j = 0; j < 8; ++j) hv[j] = bf2f(H[(kk[j] & 0x1FFFF) * DF + lane]);
        #pragma unroll
        for (int j = 0; j < 8; ++j) acc += vv[j] * hv[j];
    }
    for (; i < end; ++i)
        acc += bf2f(vals[i]) * bf2f(H[(keys[i] & 0x1FFFF) * DF + lane]);

    out[node * DF + lane] = acc;
}

extern "C" void kernel_launch(void* const* d_in, const int* in_sizes, int n_in,
                              void* d_out, int out_size, void* d_ws, size_t ws_size,
                              hipStream_t stream)
{
    const float* x    = (const float*)d_in[0];
    const float* w    = (const float*)d_in[1];
    const float* ev   = (const float*)d_in[2];
    const int*   erow = (const int*)d_in[3];
    const int*   ecol = (const int*)d_in[4];
    float* out = (float*)d_out;

    char* ws = (char*)d_ws;
    ushort* H     = (ushort*)(ws + OFF_H);
    int*    keys  = (int*)   (ws + OFF_KEYS);
    ushort* vals  = (ushort*)(ws + OFF_VALS);
    int*    ends  = (int*)   (ws + OFF_ENDS);
    int*    bases = (int*)   (ws + OFF_BASES);
    int*    curs  = (int*)   (ws + OFF_CURS);
    int*    cnts  = (int*)   (ws + OFF_CNTS);

    hipMemsetAsync(cnts, 0, NBUCK * sizeof(int), stream);
    gemm_h  <<<N_NODES / 4, 256, 0, stream>>>(x, w, H);
    bhist   <<<NCHUNK, 256, 0, stream>>>(erow, cnts);
    bscan   <<<1, 1024, 0, stream>>>(cnts, bases, curs);
    bscatter<<<NCHUNK, 256, 0, stream>>>(erow, ecol, ev, curs, keys, vals);
    bsort   <<<NBUCK, 256, 0, stream>>>(bases, keys, vals, ends);
    agg     <<<N_NODES / 4, 256, 0, stream>>>(H, ends, keys, vals, out);
}